// Round 3
// baseline (1020.330 us; speedup 1.0000x reference)
//
#include <hip/hip_runtime.h>
#include <hip/hip_bf16.h>
#include <math.h>

// Problem constants (B=64, S=512, D=256, L=3)
#define D_HID 256
#define N_B   64
#define S_LEN 512
#define N_L   3
#define M_ROWS (N_B * S_LEN)   // 32768 rows

typedef __bf16 bf16_t;
typedef __bf16 bf16x8 __attribute__((ext_vector_type(8)));
typedef __bf16 bf16x4 __attribute__((ext_vector_type(4)));
typedef float  f32x4  __attribute__((ext_vector_type(4)));
typedef unsigned int u32;

__device__ __forceinline__ f32x4 mfma16(bf16x8 a, bf16x8 b, f32x4 c) {
    return __builtin_amdgcn_mfma_f32_16x16x32_bf16(a, b, c, 0, 0, 0);
}

// async global->LDS, 16B per lane; LDS dest = wave-uniform base + lane*16
__device__ __forceinline__ void gld_lds16(const void* g, void* l) {
    __builtin_amdgcn_global_load_lds((const __attribute__((address_space(1))) u32*)g,
                                     (__attribute__((address_space(3))) u32*)l, 16, 0, 0);
}

__device__ __forceinline__ u32 pk_bf16(float a, float b) {
    return (u32)(__hip_bfloat16_raw(__hip_bfloat16(a)).x) |
           ((u32)(__hip_bfloat16_raw(__hip_bfloat16(b)).x) << 16);
}

// ---------------------------------------------------------------------------
// Weight transpose + bf16 convert: w[l][k][n] (f32) -> wt[l*ls + n*256 + k]
// ---------------------------------------------------------------------------
__global__ __launch_bounds__(256) void transpose_w(const float* __restrict__ w,
                                                   bf16_t* __restrict__ wt,
                                                   int layer_stride) {
    int i = blockIdx.x * 256 + threadIdx.x;   // total = L*D*D = 196608
    int k = i & 255;
    int n = (i >> 8) & 255;
    int l = i >> 16;
    wt[(size_t)l * layer_stride + n * 256 + k] =
        (bf16_t)w[((size_t)l << 16) + ((size_t)k << 8) + n];
}

// ---------------------------------------------------------------------------
// LayerNorm: H = LN(in)*g + b  (f32 out + bf16 copy). One wave per row.
// ---------------------------------------------------------------------------
__global__ __launch_bounds__(256) void ln_fwd(const float* __restrict__ in,
                                              const float* __restrict__ g,
                                              const float* __restrict__ b,
                                              float* __restrict__ H,
                                              bf16_t* __restrict__ Hb) {
    int row  = blockIdx.x * 4 + (threadIdx.x >> 6);
    int lane = threadIdx.x & 63;
    float4 x = ((const float4*)(in + (size_t)row * D_HID))[lane];
    float s  = x.x + x.y + x.z + x.w;
    float sq = x.x * x.x + x.y * x.y + x.z * x.z + x.w * x.w;
#pragma unroll
    for (int o = 1; o < 64; o <<= 1) { s += __shfl_xor(s, o); sq += __shfl_xor(sq, o); }
    float mean = s * (1.f / D_HID);
    float rstd = rsqrtf(sq * (1.f / D_HID) - mean * mean + 1e-5f);
    float4 gv = ((const float4*)g)[lane];
    float4 bv = ((const float4*)b)[lane];
    float4 h;
    h.x = (x.x - mean) * rstd * gv.x + bv.x;
    h.y = (x.y - mean) * rstd * gv.y + bv.y;
    h.z = (x.z - mean) * rstd * gv.z + bv.z;
    h.w = (x.w - mean) * rstd * gv.w + bv.w;
    ((float4*)(H + (size_t)row * D_HID))[lane] = h;
    bf16x4 hb = { (bf16_t)h.x, (bf16_t)h.y, (bf16_t)h.z, (bf16_t)h.w };
    *((bf16x4*)(Hb + (size_t)row * D_HID) + lane) = hb;
}

// ---------------------------------------------------------------------------
// Fused: X = H + LN(T)*g + b ; Cb = bf16( LN(X)*cg + cb ). One wave per row.
// ---------------------------------------------------------------------------
__global__ __launch_bounds__(256) void ln_res_ln(const float* __restrict__ T,
                                                 const float* __restrict__ H,
                                                 const float* __restrict__ g,
                                                 const float* __restrict__ b,
                                                 const float* __restrict__ cg,
                                                 const float* __restrict__ cb,
                                                 float* __restrict__ X,
                                                 bf16_t* __restrict__ Cb) {
    int row  = blockIdx.x * 4 + (threadIdx.x >> 6);
    int lane = threadIdx.x & 63;
    float4 t = ((const float4*)(T + (size_t)row * D_HID))[lane];
    float s  = t.x + t.y + t.z + t.w;
    float sq = t.x * t.x + t.y * t.y + t.z * t.z + t.w * t.w;
#pragma unroll
    for (int o = 1; o < 64; o <<= 1) { s += __shfl_xor(s, o); sq += __shfl_xor(sq, o); }
    float mean = s * (1.f / D_HID);
    float rstd = rsqrtf(sq * (1.f / D_HID) - mean * mean + 1e-5f);
    float4 gv = ((const float4*)g)[lane];
    float4 bv = ((const float4*)b)[lane];
    float4 hh = ((const float4*)(H + (size_t)row * D_HID))[lane];
    float4 x;
    x.x = hh.x + (t.x - mean) * rstd * gv.x + bv.x;
    x.y = hh.y + (t.y - mean) * rstd * gv.y + bv.y;
    x.z = hh.z + (t.z - mean) * rstd * gv.z + bv.z;
    x.w = hh.w + (t.w - mean) * rstd * gv.w + bv.w;
    ((float4*)(X + (size_t)row * D_HID))[lane] = x;
    // second LN
    float s2  = x.x + x.y + x.z + x.w;
    float sq2 = x.x * x.x + x.y * x.y + x.z * x.z + x.w * x.w;
#pragma unroll
    for (int o = 1; o < 64; o <<= 1) { s2 += __shfl_xor(s2, o); sq2 += __shfl_xor(sq2, o); }
    float mean2 = s2 * (1.f / D_HID);
    float rstd2 = rsqrtf(sq2 * (1.f / D_HID) - mean2 * mean2 + 1e-5f);
    float4 cgv = ((const float4*)cg)[lane];
    float4 cbv = ((const float4*)cb)[lane];
    bf16x4 c = { (bf16_t)((x.x - mean2) * rstd2 * cgv.x + cbv.x),
                 (bf16_t)((x.y - mean2) * rstd2 * cgv.y + cbv.y),
                 (bf16_t)((x.z - mean2) * rstd2 * cgv.z + cbv.z),
                 (bf16_t)((x.w - mean2) * rstd2 * cgv.w + cbv.w) };
    *((bf16x4*)(Cb + (size_t)row * D_HID) + lane) = c;
}

// ---------------------------------------------------------------------------
// GEMM core: 128x128 tile, BK=64, LDS-staged (global_load_lds w=16), XOR
// swizzle: linear LDS dest + inverse-permuted global source + XOR on ds_read.
// ---------------------------------------------------------------------------
__device__ __forceinline__ void gemm_core(const bf16_t* __restrict__ A,
                                          const bf16_t* __restrict__ W,
                                          int m0, int n0,
                                          bf16_t* As, bf16_t* Bs,
                                          f32x4 (&acc)[4][4]) {
    const int tid  = threadIdx.x;
    const int lane = tid & 63;
    const int wid  = tid >> 6;
    const int wm = wid >> 1, wn = wid & 1;
    const int r = lane & 15, g = lane >> 4;
#pragma unroll 1
    for (int kt = 0; kt < 4; ++kt) {
        if (kt) __syncthreads();
#pragma unroll
        for (int i = 0; i < 4; ++i) {
            const int base8 = i * 256 + wid * 64;          // wave-uniform
            const int idx8  = base8 + lane;
            const int row   = idx8 >> 3;
            const int sc8   = (idx8 & 7) ^ (row & 7);      // inverse swizzle on SRC
            gld_lds16(A + (size_t)(m0 + row) * D_HID + kt * 64 + sc8 * 8, As + base8 * 8);
            gld_lds16(W + (size_t)(n0 + row) * D_HID + kt * 64 + sc8 * 8, Bs + base8 * 8);
        }
        __syncthreads();
#pragma unroll
        for (int ks = 0; ks < 2; ++ks) {
            bf16x8 af[4], bfr[4];
#pragma unroll
            for (int mt = 0; mt < 4; ++mt) {
                const int row = wm * 64 + mt * 16 + r;
                const int c8  = (ks * 4 + g) ^ (row & 7);  // swizzle on READ
                af[mt] = *(const bf16x8*)(As + row * 64 + c8 * 8);
            }
#pragma unroll
            for (int nt = 0; nt < 4; ++nt) {
                const int row = wn * 64 + nt * 16 + r;
                const int c8  = (ks * 4 + g) ^ (row & 7);
                bfr[nt] = *(const bf16x8*)(Bs + row * 64 + c8 * 8);
            }
#pragma unroll
            for (int mt = 0; mt < 4; ++mt)
#pragma unroll
                for (int nt = 0; nt < 4; ++nt)
                    acc[mt][nt] = mfma16(af[mt], bfr[nt], acc[mt][nt]);
        }
    }
}

// Fused QKV GEMM: Wp packed [768][256], cols 0-255->Qb, 256-511->Kb,
// 512-767 -> Vt (transposed [b][d][s]). Grid (M/128, 6).
__global__ __launch_bounds__(256) void gemm_qkv(const bf16_t* __restrict__ A,
                                                const bf16_t* __restrict__ Wp,
                                                const float* __restrict__ bq,
                                                const float* __restrict__ bk,
                                                const float* __restrict__ bv,
                                                bf16_t* __restrict__ Qb,
                                                bf16_t* __restrict__ Kb,
                                                bf16_t* __restrict__ Vt) {
    __shared__ bf16_t As[128 * 64], Bs[128 * 64];
    f32x4 acc[4][4] = {};
    const int m0 = blockIdx.x * 128, n0 = blockIdx.y * 128;
    gemm_core(A, Wp, m0, n0, As, Bs, acc);
    const int lane = threadIdx.x & 63, wid = threadIdx.x >> 6;
    const int wm = wid >> 1, wn = wid & 1, r = lane & 15, g = lane >> 4;
#pragma unroll
    for (int nt = 0; nt < 4; ++nt) {
        const int col = n0 + wn * 64 + nt * 16 + r;
        const int t = col >> 8, cc = col & 255;
        const float bias = (t == 0 ? bq : t == 1 ? bk : bv)[cc];
#pragma unroll
        for (int mt = 0; mt < 4; ++mt)
#pragma unroll
            for (int rr = 0; rr < 4; ++rr) {
                const int row = m0 + wm * 64 + mt * 16 + g * 4 + rr;
                const float v = acc[mt][nt][rr] + bias;
                if (t == 0)      Qb[(size_t)row * D_HID + cc] = (bf16_t)v;
                else if (t == 1) Kb[(size_t)row * D_HID + cc] = (bf16_t)v;
                else             Vt[((size_t)(row >> 9) * D_HID + cc) * S_LEN + (row & 511)] = (bf16_t)v;
            }
    }
}

// Generic GEMM, N=256. EPI 1: gelu->bf16  2: f32  3: addsrc+ -> f32
template <int EPI>
__global__ __launch_bounds__(256) void gemm_one(const bf16_t* __restrict__ A,
                                                const bf16_t* __restrict__ W,
                                                const float* __restrict__ bias,
                                                void* __restrict__ outp,
                                                const float* __restrict__ addsrc) {
    __shared__ bf16_t As[128 * 64], Bs[128 * 64];
    f32x4 acc[4][4] = {};
    const int m0 = blockIdx.x * 128, n0 = blockIdx.y * 128;
    gemm_core(A, W, m0, n0, As, Bs, acc);
    const int lane = threadIdx.x & 63, wid = threadIdx.x >> 6;
    const int wm = wid >> 1, wn = wid & 1, r = lane & 15, g = lane >> 4;
#pragma unroll
    for (int nt = 0; nt < 4; ++nt) {
        const int col = n0 + wn * 64 + nt * 16 + r;
        const float bv = bias[col];
#pragma unroll
        for (int mt = 0; mt < 4; ++mt)
#pragma unroll
            for (int rr = 0; rr < 4; ++rr) {
                const size_t idx = (size_t)(m0 + wm * 64 + mt * 16 + g * 4 + rr) * D_HID + col;
                float v = acc[mt][nt][rr] + bv;
                if constexpr (EPI == 1) {
                    v = 0.5f * v * (1.f + erff(v * 0.70710678118654752f));
                    ((bf16_t*)outp)[idx] = (bf16_t)v;
                } else if constexpr (EPI == 2) {
                    ((float*)outp)[idx] = v;
                } else {
                    ((float*)outp)[idx] = addsrc[idx] + v;
                }
            }
    }
}

// ---------------------------------------------------------------------------
// Flash attention, intra-block split-K. Grid: 1024 blocks (XCD-chunked
// mapping), 4 waves. Wave w owns keys [w*128, w*128+128) with private online
// softmax (swapped QK^T => S^T; softmax = in-lane + 2 shfl_xor). P staged in
// per-wave LDS [32][144B] (no barrier, same-wave). PV: P A-frags contiguous,
// V B-frags contiguous from Vt[b][d][s]. End: 4-round LDS merge of partials.
// ---------------------------------------------------------------------------
__global__ __launch_bounds__(256, 2) void attn_fwd(const bf16_t* __restrict__ Q,
                                                   const bf16_t* __restrict__ K,
                                                   const bf16_t* __restrict__ Vt,
                                                   const float* __restrict__ btab,
                                                   const int* __restrict__ mask,
                                                   bf16_t* __restrict__ AO) {
    __shared__ float bias_lds[1024];
    __shared__ float mask_add[512];
    __shared__ ulong pstage[4][32][18];     // row stride 144B (16-aligned, skewed)
    __shared__ float m_buf[4][32], l_buf[4][32];
    __shared__ float o_merge[32][256];

    const int tid = threadIdx.x, lane = tid & 63, w = tid >> 6;
    const int r = lane & 15, g = lane >> 4;

    // XCD-chunked block mapping: 8 batches per XCD -> K/V L2-resident
    const int lid = blockIdx.x;
    const int xcd = lid & 7, slot = lid >> 3;
    const int b  = xcd * 8 + (slot >> 4);
    const int q0 = (slot & 15) * 32;

    // prologue: bias-by-rel and mask-additive tables
    for (int i = tid; i < 1024; i += 256) {
        const int rel = i - 512;
        const int bucket = (rel < 0) ? (511 - rel) : rel;
        bias_lds[i] = btab[bucket];
    }
    for (int i = tid; i < 512; i += 256)
        mask_add[i] = mask[b * S_LEN + i] ? 0.f : -3.0e38f;
    __syncthreads();

    const bf16_t* Qp = Q  + ((size_t)b * S_LEN + q0) * D_HID;
    const bf16_t* Kp = K  + (size_t)b * S_LEN * D_HID;
    const bf16_t* Vp = Vt + (size_t)b * D_HID * S_LEN;
    char* pst = (char*)&pstage[w][0][0];

    f32x4 oacc[2][16] = {};
    float m_run[2] = {-3.0e38f, -3.0e38f};
    float l_run[2] = {0.f, 0.f};

#pragma unroll 1
    for (int kt = 0; kt < 2; ++kt) {
        const int k0 = (w * 2 + kt) * 64;
        // ---- QK^T swapped: sacc[mt][nt2] = S^T tile, A=K rows, B=Q rows
        f32x4 sacc[4][2] = {};
#pragma unroll
        for (int ks = 0; ks < 8; ++ks) {
            const int dk = ks * 32 + g * 8;
            bf16x8 qf0 = *(const bf16x8*)(Qp + (size_t)r * D_HID + dk);
            bf16x8 qf1 = *(const bf16x8*)(Qp + (size_t)(16 + r) * D_HID + dk);
            bf16x8 kf[4];
#pragma unroll
            for (int mt = 0; mt < 4; ++mt)
                kf[mt] = *(const bf16x8*)(Kp + (size_t)(k0 + mt * 16 + r) * D_HID + dk);
            __builtin_amdgcn_s_setprio(1);
#pragma unroll
            for (int mt = 0; mt < 4; ++mt) {
                sacc[mt][0] = mfma16(kf[mt], qf0, sacc[mt][0]);
                sacc[mt][1] = mfma16(kf[mt], qf1, sacc[mt][1]);
            }
            __builtin_amdgcn_s_setprio(0);
        }
        // ---- softmax (per-lane: q in {q0+r, q0+16+r}, k = k0+mt*16+g*4+rr)
        float mx[2] = {-3.0e38f, -3.0e38f};
#pragma unroll
        for (int mt = 0; mt < 4; ++mt)
#pragma unroll
            for (int rr = 0; rr < 4; ++rr) {
                const int kg = k0 + mt * 16 + g * 4 + rr;
                const float ma = mask_add[kg];
#pragma unroll
                for (int nt2 = 0; nt2 < 2; ++nt2) {
                    const int rel = kg - (q0 + nt2 * 16 + r);
                    float ev = sacc[mt][nt2][rr] * 0.0625f + bias_lds[rel + 512] + ma;
                    sacc[mt][nt2][rr] = ev;
                    mx[nt2] = fmaxf(mx[nt2], ev);
                }
            }
#pragma unroll
        for (int nt2 = 0; nt2 < 2; ++nt2) {
            mx[nt2] = fmaxf(mx[nt2], __shfl_xor(mx[nt2], 16));
            mx[nt2] = fmaxf(mx[nt2], __shfl_xor(mx[nt2], 32));
        }
        float mnew[2], fac[2], ladd[2] = {0.f, 0.f};
#pragma unroll
        for (int nt2 = 0; nt2 < 2; ++nt2) {
            mnew[nt2] = fmaxf(m_run[nt2], mx[nt2]);
            fac[nt2]  = __expf(m_run[nt2] - mnew[nt2]);
        }
#pragma unroll
        for (int mt = 0; mt < 4; ++mt)
#pragma unroll
            for (int nt2 = 0; nt2 < 2; ++nt2)
#pragma unroll
                for (int rr = 0; rr < 4; ++rr) {
                    const float p = __expf(sacc[mt][nt2][rr] - mnew[nt2]);
                    sacc[mt][nt2][rr] = p;
                    ladd[nt2] += p;
                }
#pragma unroll
        for (int nt2 = 0; nt2 < 2; ++nt2) {
            ladd[nt2] += __shfl_xor(ladd[nt2], 16);
            ladd[nt2] += __shfl_xor(ladd[nt2], 32);
            l_run[nt2] = l_run[nt2] * fac[nt2] + ladd[nt2];
            m_run[nt2] = mnew[nt2];
        }
        // ---- stage P: [q][k] rows of 144B; lane writes 8B (4 k-consecutive)
#pragma unroll
        for (int nt2 = 0; nt2 < 2; ++nt2)
#pragma unroll
            for (int mt = 0; mt < 4; ++mt) {
                const u32 lo = pk_bf16(sacc[mt][nt2][0], sacc[mt][nt2][1]);
                const u32 hi = pk_bf16(sacc[mt][nt2][2], sacc[mt][nt2][3]);
                const int off = (nt2 * 16 + r) * 144 + mt * 32 + g * 8;
                uint2 pv; pv.x = lo; pv.y = hi;
                *(uint2*)(pst + off) = pv;
            }
        // ---- rescale O by fac at its rows (row q = mt2*16 + g*4 + rr)
        float fbc[2][4];
#pragma unroll
        for (int mt2 = 0; mt2 < 2; ++mt2)
#pragma unroll
            for (int rr = 0; rr < 4; ++rr)
                fbc[mt2][rr] = __shfl(fac[mt2], g * 4 + rr);
#pragma unroll
        for (int mt2 = 0; mt2 < 2; ++mt2)
#pragma unroll
            for (int nt = 0; nt < 16; ++nt)
#pragma unroll
                for (int rr = 0; rr < 4; ++rr)
                    oacc[mt2][nt][rr] *= fbc[mt2][rr];
        // ---- PV: A = P from LDS (contiguous), B = V from Vt (contiguous)
#pragma unroll
        for (int ks = 0; ks < 2; ++ks) {
            bf16x8 pf[2];
#pragma unroll
            for (int mt2 = 0; mt2 < 2; ++mt2)
                pf[mt2] = *(const bf16x8*)(pst + (mt2 * 16 + r) * 144 + ks * 64 + g * 16);
            __builtin_amdgcn_s_setprio(1);
#pragma unroll
            for (int nt = 0; nt < 16; ++nt) {
                bf16x8 vf = *(const bf16x8*)(Vp + (size_t)(nt * 16 + r) * S_LEN
                                                  + k0 + ks * 32 + g * 8);
                oacc[0][nt] = mfma16(pf[0], vf, oacc[0][nt]);
                oacc[1][nt] = mfma16(pf[1], vf, oacc[1][nt]);
            }
            __builtin_amdgcn_s_setprio(0);
        }
    }

    // ---- merge partials across the 4 waves
    if (g == 0) {
        m_buf[w][r]      = m_run[0];
        m_buf[w][16 + r] = m_run[1];
        l_buf[w][r]      = l_run[0];
        l_buf[w][16 + r] = l_run[1];
    }
    __syncthreads();
    float scl[2][4];
#pragma unroll
    for (int mt2 = 0; mt2 < 2; ++mt2)
#pragma unroll
        for (int rr = 0; rr < 4; ++rr) {
            const int q = mt2 * 16 + g * 4 + rr;
            float mf = m_buf[0][q];
            mf = fmaxf(mf, m_buf[1][q]);
            mf = fmaxf(mf, m_buf[2][q]);
            mf = fmaxf(mf, m_buf[3][q]);
            float lf = 0.f;
#pragma unroll
            for (int ww = 0; ww < 4; ++ww)
                lf += __expf(m_buf[ww][q] - mf) * l_buf[ww][q];
            lf = fmaxf(lf, 1e-30f);
            scl[mt2][rr] = __expf(m_buf[w][q] - mf) / lf;
        }
#pragma unroll 1
    for (int rnd = 0; rnd < 4; ++rnd) {
        if (w == rnd) {
#pragma unroll
            for (int mt2 = 0; mt2 < 2; ++mt2)
#pragma unroll
                for (int nt = 0; nt < 16; ++nt)
#pragma unroll
                    for (int rr = 0; rr < 4; ++rr) {
                        const int q = mt2 * 16 + g * 4 + rr;
                        const int d = nt * 16 + r;
                        const float v = oacc[mt2][nt][rr] * scl[mt2][rr];
                        if (rnd == 0) o_merge[q][d] = v;
                        else          o_merge[q][d] += v;
                    }
        }
        __syncthreads();
    }
    // ---- store (coalesced): 256 threads x 8 float4
    bf16_t* Op = AO + ((size_t)b * S_LEN + q0) * D_HID;
#pragma unroll
    for (int it = 0; it < 8; ++it) {
        const int idx = it * 256 + tid;         // [0, 2048) float4 units
        const int row = idx >> 6, c4 = idx & 63;
        const float4 v = *(const float4*)&o_merge[row][c4 * 4];
        bf16x4 ob = { (bf16_t)v.x, (bf16_t)v.y, (bf16_t)v.z, (bf16_t)v.w };
        *((bf16x4*)(Op + (size_t)row * D_HID) + c4) = ob;
    }
}

// ---------------------------------------------------------------------------
extern "C" void kernel_launch(void* const* d_in, const int* in_sizes, int n_in,
                              void* d_out, int out_size, void* d_ws, size_t ws_size,
                              hipStream_t stream) {
    const float* x_in = (const float*)d_in[0];
    const int*   mask = (const int*)d_in[1];
    const float* btab = (const float*)d_in[2];
    const float* ln_g = (const float*)d_in[3];
    const float* ln_b = (const float*)d_in[4];
    const float* wq = (const float*)d_in[5];
    const float* bq = (const float*)d_in[6];
    const float* wk = (const float*)d_in[7];
    const float* bk = (const float*)d_in[8];
    const float* wv = (const float*)d_in[9];
    const float* bv = (const float*)d_in[10];
    const float* wo = (const float*)d_in[11];
    const float* bo = (const float*)d_in[12];
    const float* cg = (const float*)d_in[13];
    const float* cb = (const float*)d_in[14];
    const float* w1 = (const float*)d_in[15];
    const float* b1 = (const float*)d_in[16];
    const float* w2 = (const float*)d_in[17];
    const float* b2 = (const float*)d_in[18];
    float* out = (float*)d_out;

    // Workspace layout (~137 MB), regions reused across stage lifetimes.
    char* p = (char*)d_ws;
    const size_t F32SZ  = (size_t)M_ROWS * D_HID * sizeof(float);   // 33.5 MB
    const size_t BF16SZ = (size_t)M_ROWS * D_HID * sizeof(bf16_t);  // 16.8 MB
    float*  H  = (float*)p;  p += F32SZ;
    float*  X  = (float*)p;  p += F32SZ;
    bf16_t* Hb = (bf16_t*)p; p += BF16SZ;   // later: AO
    bf16_t* Qb = (bf16_t*)p; p += BF16SZ;   // later: Cb
    bf16_t* Kb = (bf16_t*)p;                // T (f32) spans Kb+Vt; T1b reuses Kb
    float*  T  = (float*)Kb;
    bf16_t* T1b = Kb;
    p += BF16SZ;
    bf16_t* Vt = (bf16_t*)p; p += BF16SZ;   // transposed V [b][d][s]
    bf16_t* Wqkv = (bf16_t*)p; p += (size_t)N_L * 768 * 256 * sizeof(bf16_t);  // packed
    bf16_t* Wrest = (bf16_t*)p;             // Wo,W1,W2: 3 * L * 65536 bf16
    bf16_t* AO = Hb;
    bf16_t* Cb = Qb;

    const int WELEMS = N_L * D_HID * D_HID;   // 196608 per weight tensor
    transpose_w<<<dim3(WELEMS / 256), dim3(256), 0, stream>>>(wq, Wqkv + 0 * 65536, 3 * 65536);
    transpose_w<<<dim3(WELEMS / 256), dim3(256), 0, stream>>>(wk, Wqkv + 1 * 65536, 3 * 65536);
    transpose_w<<<dim3(WELEMS / 256), dim3(256), 0, stream>>>(wv, Wqkv + 2 * 65536, 3 * 65536);
    transpose_w<<<dim3(WELEMS / 256), dim3(256), 0, stream>>>(wo, Wrest + (size_t)0 * WELEMS, 65536);
    transpose_w<<<dim3(WELEMS / 256), dim3(256), 0, stream>>>(w1, Wrest + (size_t)1 * WELEMS, 65536);
    transpose_w<<<dim3(WELEMS / 256), dim3(256), 0, stream>>>(w2, Wrest + (size_t)2 * WELEMS, 65536);

    const dim3 gblk(256, 1, 1);
    const dim3 grid_qkv(M_ROWS / 128, 6, 1);
    const dim3 grid_one(M_ROWS / 128, 2, 1);

    for (int j = 0; j < N_L; ++j) {
        const bf16_t* WQKVj = Wqkv + (size_t)j * 3 * 65536;
        const bf16_t* WOt = Wrest + ((size_t)0 * N_L + j) * 65536;
        const bf16_t* W1t = Wrest + ((size_t)1 * N_L + j) * 65536;
        const bf16_t* W2t = Wrest + ((size_t)2 * N_L + j) * 65536;

        ln_fwd<<<dim3(M_ROWS / 4), gblk, 0, stream>>>(j == 0 ? x_in : X,
                                                      ln_g + j * D_HID, ln_b + j * D_HID, H, Hb);
        gemm_qkv<<<grid_qkv, gblk, 0, stream>>>(Hb, WQKVj, bq + j * D_HID, bk + j * D_HID,
                                                bv + j * D_HID, Qb, Kb, Vt);
        attn_fwd<<<dim3(N_B * 16, 1, 1), gblk, 0, stream>>>(Qb, Kb, Vt, btab, mask, AO);
        gemm_one<2><<<grid_one, gblk, 0, stream>>>(AO, WOt, bo + j * D_HID, T, nullptr);
        ln_res_ln<<<dim3(M_ROWS / 4), gblk, 0, stream>>>(T, H, ln_g + j * D_HID, ln_b + j * D_HID,
                                                         cg + j * D_HID, cb + j * D_HID, X, Cb);
        gemm_one<1><<<grid_one, gblk, 0, stream>>>(Cb, W1t, b1 + j * D_HID, T1b, nullptr);
        gemm_one<3><<<grid_one, gblk, 0, stream>>>(T1b, W2t, b2 + j * D_HID,
                                                   (j == N_L - 1) ? (void*)out : (void*)X, X);
    }
}

// Round 4
// 715.783 us; speedup vs baseline: 1.4255x; 1.4255x over previous
//
#include <hip/hip_runtime.h>
#include <hip/hip_bf16.h>
#include <math.h>

// Problem constants (B=64, S=512, D=256, L=3)
#define D_HID 256
#define N_B   64
#define S_LEN 512
#define N_L   3
#define M_ROWS (N_B * S_LEN)   // 32768 rows

typedef __bf16 bf16_t;
typedef __bf16 bf16x8 __attribute__((ext_vector_type(8)));
typedef __bf16 bf16x4 __attribute__((ext_vector_type(4)));
typedef float  f32x4  __attribute__((ext_vector_type(4)));
typedef unsigned int u32;

__device__ __forceinline__ f32x4 mfma16(bf16x8 a, bf16x8 b, f32x4 c) {
    return __builtin_amdgcn_mfma_f32_16x16x32_bf16(a, b, c, 0, 0, 0);
}

// async global->LDS, 16B per lane; LDS dest = wave-uniform base + lane*16
__device__ __forceinline__ void gld_lds16(const void* g, void* l) {
    __builtin_amdgcn_global_load_lds((const __attribute__((address_space(1))) u32*)g,
                                     (__attribute__((address_space(3))) u32*)l, 16, 0, 0);
}

__device__ __forceinline__ u32 pk_bf16(float a, float b) {
    return (u32)(__hip_bfloat16_raw(__hip_bfloat16(a)).x) |
           ((u32)(__hip_bfloat16_raw(__hip_bfloat16(b)).x) << 16);
}

// ---------------------------------------------------------------------------
// Weight transpose + bf16 convert: w[l][k][n] (f32) -> wt[l*ls + n*256 + k]
// ---------------------------------------------------------------------------
__global__ __launch_bounds__(256) void transpose_w(const float* __restrict__ w,
                                                   bf16_t* __restrict__ wt,
                                                   int layer_stride) {
    int i = blockIdx.x * 256 + threadIdx.x;   // total = L*D*D = 196608
    int k = i & 255;
    int n = (i >> 8) & 255;
    int l = i >> 16;
    wt[(size_t)l * layer_stride + n * 256 + k] =
        (bf16_t)w[((size_t)l << 16) + ((size_t)k << 8) + n];
}

// ---------------------------------------------------------------------------
// LayerNorm: H = LN(in)*g + b  (f32 out + bf16 copy). One wave per row.
// ---------------------------------------------------------------------------
__global__ __launch_bounds__(256) void ln_fwd(const float* __restrict__ in,
                                              const float* __restrict__ g,
                                              const float* __restrict__ b,
                                              float* __restrict__ H,
                                              bf16_t* __restrict__ Hb) {
    int row  = blockIdx.x * 4 + (threadIdx.x >> 6);
    int lane = threadIdx.x & 63;
    float4 x = ((const float4*)(in + (size_t)row * D_HID))[lane];
    float s  = x.x + x.y + x.z + x.w;
    float sq = x.x * x.x + x.y * x.y + x.z * x.z + x.w * x.w;
#pragma unroll
    for (int o = 1; o < 64; o <<= 1) { s += __shfl_xor(s, o); sq += __shfl_xor(sq, o); }
    float mean = s * (1.f / D_HID);
    float rstd = rsqrtf(sq * (1.f / D_HID) - mean * mean + 1e-5f);
    float4 gv = ((const float4*)g)[lane];
    float4 bv = ((const float4*)b)[lane];
    float4 h;
    h.x = (x.x - mean) * rstd * gv.x + bv.x;
    h.y = (x.y - mean) * rstd * gv.y + bv.y;
    h.z = (x.z - mean) * rstd * gv.z + bv.z;
    h.w = (x.w - mean) * rstd * gv.w + bv.w;
    ((float4*)(H + (size_t)row * D_HID))[lane] = h;
    bf16x4 hb = { (bf16_t)h.x, (bf16_t)h.y, (bf16_t)h.z, (bf16_t)h.w };
    *((bf16x4*)(Hb + (size_t)row * D_HID) + lane) = hb;
}

// ---------------------------------------------------------------------------
// Fused: X = H + LN(T)*g + b ; Cb = bf16( LN(X)*cg + cb ). One wave per row.
// ---------------------------------------------------------------------------
__global__ __launch_bounds__(256) void ln_res_ln(const float* __restrict__ T,
                                                 const float* __restrict__ H,
                                                 const float* __restrict__ g,
                                                 const float* __restrict__ b,
                                                 const float* __restrict__ cg,
                                                 const float* __restrict__ cb,
                                                 float* __restrict__ X,
                                                 bf16_t* __restrict__ Cb) {
    int row  = blockIdx.x * 4 + (threadIdx.x >> 6);
    int lane = threadIdx.x & 63;
    float4 t = ((const float4*)(T + (size_t)row * D_HID))[lane];
    float s  = t.x + t.y + t.z + t.w;
    float sq = t.x * t.x + t.y * t.y + t.z * t.z + t.w * t.w;
#pragma unroll
    for (int o = 1; o < 64; o <<= 1) { s += __shfl_xor(s, o); sq += __shfl_xor(sq, o); }
    float mean = s * (1.f / D_HID);
    float rstd = rsqrtf(sq * (1.f / D_HID) - mean * mean + 1e-5f);
    float4 gv = ((const float4*)g)[lane];
    float4 bv = ((const float4*)b)[lane];
    float4 hh = ((const float4*)(H + (size_t)row * D_HID))[lane];
    float4 x;
    x.x = hh.x + (t.x - mean) * rstd * gv.x + bv.x;
    x.y = hh.y + (t.y - mean) * rstd * gv.y + bv.y;
    x.z = hh.z + (t.z - mean) * rstd * gv.z + bv.z;
    x.w = hh.w + (t.w - mean) * rstd * gv.w + bv.w;
    ((float4*)(X + (size_t)row * D_HID))[lane] = x;
    // second LN
    float s2  = x.x + x.y + x.z + x.w;
    float sq2 = x.x * x.x + x.y * x.y + x.z * x.z + x.w * x.w;
#pragma unroll
    for (int o = 1; o < 64; o <<= 1) { s2 += __shfl_xor(s2, o); sq2 += __shfl_xor(sq2, o); }
    float mean2 = s2 * (1.f / D_HID);
    float rstd2 = rsqrtf(sq2 * (1.f / D_HID) - mean2 * mean2 + 1e-5f);
    float4 cgv = ((const float4*)cg)[lane];
    float4 cbv = ((const float4*)cb)[lane];
    bf16x4 c = { (bf16_t)((x.x - mean2) * rstd2 * cgv.x + cbv.x),
                 (bf16_t)((x.y - mean2) * rstd2 * cgv.y + cbv.y),
                 (bf16_t)((x.z - mean2) * rstd2 * cgv.z + cbv.z),
                 (bf16_t)((x.w - mean2) * rstd2 * cgv.w + cbv.w) };
    *((bf16x4*)(Cb + (size_t)row * D_HID) + lane) = c;
}

// ---------------------------------------------------------------------------
// GEMM core: 128x128 tile, BK=64, LDS-staged (global_load_lds w=16), XOR
// swizzle: linear LDS dest + inverse-permuted global source + XOR on ds_read.
// ---------------------------------------------------------------------------
__device__ __forceinline__ void gemm_core(const bf16_t* __restrict__ A,
                                          const bf16_t* __restrict__ W,
                                          int m0, int n0,
                                          bf16_t* As, bf16_t* Bs,
                                          f32x4 (&acc)[4][4]) {
    const int tid  = threadIdx.x;
    const int lane = tid & 63;
    const int wid  = tid >> 6;
    const int wm = wid >> 1, wn = wid & 1;
    const int r = lane & 15, g = lane >> 4;
#pragma unroll 1
    for (int kt = 0; kt < 4; ++kt) {
        if (kt) __syncthreads();
#pragma unroll
        for (int i = 0; i < 4; ++i) {
            const int base8 = i * 256 + wid * 64;          // wave-uniform
            const int idx8  = base8 + lane;
            const int row   = idx8 >> 3;
            const int sc8   = (idx8 & 7) ^ (row & 7);      // inverse swizzle on SRC
            gld_lds16(A + (size_t)(m0 + row) * D_HID + kt * 64 + sc8 * 8, As + base8 * 8);
            gld_lds16(W + (size_t)(n0 + row) * D_HID + kt * 64 + sc8 * 8, Bs + base8 * 8);
        }
        __syncthreads();
#pragma unroll
        for (int ks = 0; ks < 2; ++ks) {
            bf16x8 af[4], bfr[4];
#pragma unroll
            for (int mt = 0; mt < 4; ++mt) {
                const int row = wm * 64 + mt * 16 + r;
                const int c8  = (ks * 4 + g) ^ (row & 7);  // swizzle on READ
                af[mt] = *(const bf16x8*)(As + row * 64 + c8 * 8);
            }
#pragma unroll
            for (int nt = 0; nt < 4; ++nt) {
                const int row = wn * 64 + nt * 16 + r;
                const int c8  = (ks * 4 + g) ^ (row & 7);
                bfr[nt] = *(const bf16x8*)(Bs + row * 64 + c8 * 8);
            }
#pragma unroll
            for (int mt = 0; mt < 4; ++mt)
#pragma unroll
                for (int nt = 0; nt < 4; ++nt)
                    acc[mt][nt] = mfma16(af[mt], bfr[nt], acc[mt][nt]);
        }
    }
}

// Fused QKV GEMM: Wp packed [768][256], cols 0-255->Qb, 256-511->Kb,
// 512-767 -> Vt (transposed [b][d][s]). Grid (M/128, 6).
__global__ __launch_bounds__(256) void gemm_qkv(const bf16_t* __restrict__ A,
                                                const bf16_t* __restrict__ Wp,
                                                const float* __restrict__ bq,
                                                const float* __restrict__ bk,
                                                const float* __restrict__ bv,
                                                bf16_t* __restrict__ Qb,
                                                bf16_t* __restrict__ Kb,
                                                bf16_t* __restrict__ Vt) {
    __shared__ bf16_t As[128 * 64], Bs[128 * 64];
    f32x4 acc[4][4] = {};
    const int m0 = blockIdx.x * 128, n0 = blockIdx.y * 128;
    gemm_core(A, Wp, m0, n0, As, Bs, acc);
    const int lane = threadIdx.x & 63, wid = threadIdx.x >> 6;
    const int wm = wid >> 1, wn = wid & 1, r = lane & 15, g = lane >> 4;
#pragma unroll
    for (int nt = 0; nt < 4; ++nt) {
        const int col = n0 + wn * 64 + nt * 16 + r;
        const int t = col >> 8, cc = col & 255;
        const float bias = (t == 0 ? bq : t == 1 ? bk : bv)[cc];
#pragma unroll
        for (int mt = 0; mt < 4; ++mt)
#pragma unroll
            for (int rr = 0; rr < 4; ++rr) {
                const int row = m0 + wm * 64 + mt * 16 + g * 4 + rr;
                const float v = acc[mt][nt][rr] + bias;
                if (t == 0)      Qb[(size_t)row * D_HID + cc] = (bf16_t)v;
                else if (t == 1) Kb[(size_t)row * D_HID + cc] = (bf16_t)v;
                else             Vt[((size_t)(row >> 9) * D_HID + cc) * S_LEN + (row & 511)] = (bf16_t)v;
            }
    }
}

// Generic GEMM, N=256. EPI 1: gelu->bf16  2: f32  3: addsrc+ -> f32
template <int EPI>
__global__ __launch_bounds__(256) void gemm_one(const bf16_t* __restrict__ A,
                                                const bf16_t* __restrict__ W,
                                                const float* __restrict__ bias,
                                                void* __restrict__ outp,
                                                const float* __restrict__ addsrc) {
    __shared__ bf16_t As[128 * 64], Bs[128 * 64];
    f32x4 acc[4][4] = {};
    const int m0 = blockIdx.x * 128, n0 = blockIdx.y * 128;
    gemm_core(A, W, m0, n0, As, Bs, acc);
    const int lane = threadIdx.x & 63, wid = threadIdx.x >> 6;
    const int wm = wid >> 1, wn = wid & 1, r = lane & 15, g = lane >> 4;
#pragma unroll
    for (int nt = 0; nt < 4; ++nt) {
        const int col = n0 + wn * 64 + nt * 16 + r;
        const float bv = bias[col];
#pragma unroll
        for (int mt = 0; mt < 4; ++mt)
#pragma unroll
            for (int rr = 0; rr < 4; ++rr) {
                const size_t idx = (size_t)(m0 + wm * 64 + mt * 16 + g * 4 + rr) * D_HID + col;
                float v = acc[mt][nt][rr] + bv;
                if constexpr (EPI == 1) {
                    v = 0.5f * v * (1.f + erff(v * 0.70710678118654752f));
                    ((bf16_t*)outp)[idx] = (bf16_t)v;
                } else if constexpr (EPI == 2) {
                    ((float*)outp)[idx] = v;
                } else {
                    ((float*)outp)[idx] = addsrc[idx] + v;
                }
            }
    }
}

// ---------------------------------------------------------------------------
// Flash attention v4. Grid 1024 (XCD-chunked), 4 waves, QBLK=32.
// Swapped QK^T (S^T in-lane softmax, 2 shfl_xor). Waves split keys for QK
// (16 keys/wave/tile) and split d for PV (64 d/wave). P staged in LDS with
// GEMM-style XOR swizzle; V read contiguous from Vt[b][d][s]. 2 barriers/tile.
// O^T accumulator (32 VGPR), transposed via bf16 LDS at the end.
// ---------------------------------------------------------------------------
__global__ __launch_bounds__(256) void attn_fwd(const bf16_t* __restrict__ Q,
                                                const bf16_t* __restrict__ K,
                                                const bf16_t* __restrict__ Vt,
                                                const float* __restrict__ btab,
                                                const int* __restrict__ mask,
                                                bf16_t* __restrict__ AO) {
    __shared__ float  bias_lds[1024];
    __shared__ float  mask_add[512];
    __shared__ bf16_t P_lds[32 * 64];        // 4KB, row stride 128B, XOR-swizzled
    __shared__ float  m_part[4][32], l_part[4][32];
    __shared__ bf16_t o_lds[32][264];        // 16.5KB, row stride 528B

    const int tid = threadIdx.x, lane = tid & 63, w = tid >> 6;
    const int r = lane & 15, g = lane >> 4;

    // XCD-chunked mapping: 8 batches per XCD -> K/V L2-resident
    const int lid = blockIdx.x;
    const int xcd = lid & 7, slot = lid >> 3;
    const int b  = xcd * 8 + (slot >> 4);
    const int q0 = (slot & 15) * 32;

    for (int i = tid; i < 1024; i += 256) {
        const int rel = i - 512;
        const int bucket = (rel < 0) ? (511 - rel) : rel;
        bias_lds[i] = btab[bucket];
    }
    for (int i = tid; i < 512; i += 256)
        mask_add[i] = mask[b * S_LEN + i] ? 0.f : -3.0e38f;
    __syncthreads();

    const bf16_t* Qp = Q  + ((size_t)b * S_LEN + q0) * D_HID;
    const bf16_t* Kp = K  + (size_t)b * S_LEN * D_HID;
    const bf16_t* Vp = Vt + (size_t)b * D_HID * S_LEN;

    f32x4 oacc[4][2] = {};                   // [nt: d-16-blocks][qb]
    float m_run[2] = {-3.0e38f, -3.0e38f};
    float l_run[2] = {0.f, 0.f};

#pragma unroll 1
    for (int kt = 0; kt < 8; ++kt) {
        const int k0 = kt * 64;
        // ---- QK^T swapped: lane holds S^T[k = k0+w*16+g*4+rr][q = q0+qb*16+r]
        f32x4 sacc[2] = {};
#pragma unroll
        for (int ks = 0; ks < 8; ++ks) {
            const int dk = ks * 32 + g * 8;
            bf16x8 kf  = *(const bf16x8*)(Kp + (size_t)(k0 + w * 16 + r) * D_HID + dk);
            bf16x8 qf0 = *(const bf16x8*)(Qp + (size_t)r * D_HID + dk);
            bf16x8 qf1 = *(const bf16x8*)(Qp + (size_t)(16 + r) * D_HID + dk);
            sacc[0] = mfma16(kf, qf0, sacc[0]);
            sacc[1] = mfma16(kf, qf1, sacc[1]);
        }
        // ---- bias + mask + per-wave max (in-lane + shfl over g)
        float mx[2] = {-3.0e38f, -3.0e38f};
#pragma unroll
        for (int qb = 0; qb < 2; ++qb) {
            const int qg = q0 + qb * 16 + r;
#pragma unroll
            for (int rr = 0; rr < 4; ++rr) {
                const int kg = k0 + w * 16 + g * 4 + rr;
                float ev = sacc[qb][rr] * 0.0625f + bias_lds[kg - qg + 512] + mask_add[kg];
                sacc[qb][rr] = ev;
                mx[qb] = fmaxf(mx[qb], ev);
            }
            mx[qb] = fmaxf(mx[qb], __shfl_xor(mx[qb], 16));
            mx[qb] = fmaxf(mx[qb], __shfl_xor(mx[qb], 32));
        }
        if (g == 0) { m_part[w][r] = mx[0]; m_part[w][16 + r] = mx[1]; }
        __syncthreads();                                   // B1
        float mnew[2], fac[2];
#pragma unroll
        for (int qb = 0; qb < 2; ++qb) {
            const int q = qb * 16 + r;
            const float tm = fmaxf(fmaxf(m_part[0][q], m_part[1][q]),
                                   fmaxf(m_part[2][q], m_part[3][q]));
            mnew[qb] = fmaxf(m_run[qb], tm);
            fac[qb]  = __expf(m_run[qb] - mnew[qb]);
            m_run[qb] = mnew[qb];
        }
        // ---- P = exp(ev - m), l-partials, pack bf16 -> swizzled LDS
#pragma unroll
        for (int qb = 0; qb < 2; ++qb) {
            const float p0 = __expf(sacc[qb][0] - mnew[qb]);
            const float p1 = __expf(sacc[qb][1] - mnew[qb]);
            const float p2 = __expf(sacc[qb][2] - mnew[qb]);
            const float p3 = __expf(sacc[qb][3] - mnew[qb]);
            float ls = p0 + p1 + p2 + p3;
            ls += __shfl_xor(ls, 16);
            ls += __shfl_xor(ls, 32);
            if (g == 0) l_part[w][qb * 16 + r] = ls;
            const int q = qb * 16 + r;
            const int u = (2 * w + (g >> 1)) ^ (q & 7);    // 16B-unit XOR swizzle
            uint2 pv; pv.x = pk_bf16(p0, p1); pv.y = pk_bf16(p2, p3);
            *(uint2*)((char*)P_lds + q * 128 + u * 16 + (g & 1) * 8) = pv;
        }
        __syncthreads();                                   // B2
        // ---- l update + O rescale
#pragma unroll
        for (int qb = 0; qb < 2; ++qb) {
            const int q = qb * 16 + r;
            const float lt = l_part[0][q] + l_part[1][q] + l_part[2][q] + l_part[3][q];
            l_run[qb] = l_run[qb] * fac[qb] + lt;
        }
#pragma unroll
        for (int nt = 0; nt < 4; ++nt)
#pragma unroll
            for (int qb = 0; qb < 2; ++qb)
#pragma unroll
                for (int rr = 0; rr < 4; ++rr)
                    oacc[nt][qb][rr] *= fac[qb];
        // ---- PV (O^T): A = Vt d-rows (contiguous), B = P rows (swizzled LDS)
#pragma unroll
        for (int ks = 0; ks < 2; ++ks) {
            bf16x8 pf[2];
#pragma unroll
            for (int qb = 0; qb < 2; ++qb) {
                const int q = qb * 16 + r;
                const int u = (ks * 4 + g) ^ (q & 7);
                pf[qb] = *(const bf16x8*)((const char*)P_lds + q * 128 + u * 16);
            }
            __builtin_amdgcn_s_setprio(1);
#pragma unroll
            for (int nt = 0; nt < 4; ++nt) {
                bf16x8 vf = *(const bf16x8*)(Vp + (size_t)(w * 64 + nt * 16 + r) * S_LEN
                                                  + k0 + ks * 32 + g * 8);
                oacc[nt][0] = mfma16(vf, pf[0], oacc[nt][0]);
                oacc[nt][1] = mfma16(vf, pf[1], oacc[nt][1]);
            }
            __builtin_amdgcn_s_setprio(0);
        }
    }
    // ---- epilogue: scale 1/l (same across waves), transpose via LDS, store
    const float inv_l[2] = { 1.f / fmaxf(l_run[0], 1e-30f),
                             1.f / fmaxf(l_run[1], 1e-30f) };
#pragma unroll
    for (int nt = 0; nt < 4; ++nt)
#pragma unroll
        for (int qb = 0; qb < 2; ++qb) {
            const int q = qb * 16 + r;
            const int d = w * 64 + nt * 16 + g * 4;
            bf16x4 ob = { (bf16_t)(oacc[nt][qb][0] * inv_l[qb]),
                          (bf16_t)(oacc[nt][qb][1] * inv_l[qb]),
                          (bf16_t)(oacc[nt][qb][2] * inv_l[qb]),
                          (bf16_t)(oacc[nt][qb][3] * inv_l[qb]) };
            *(bf16x4*)&o_lds[q][d] = ob;
        }
    __syncthreads();
    bf16_t* Op = AO + ((size_t)b * S_LEN + q0) * D_HID;
#pragma unroll
    for (int it = 0; it < 4; ++it) {
        const int idx = it * 256 + tid;      // 1024 units = 32 rows x 32 x 16B
        const int row = idx >> 5, u = idx & 31;
        bf16x8 vv = *(const bf16x8*)&o_lds[row][u * 8];
        *(bf16x8*)(Op + (size_t)row * D_HID + u * 8) = vv;
    }
}

// ---------------------------------------------------------------------------
extern "C" void kernel_launch(void* const* d_in, const int* in_sizes, int n_in,
                              void* d_out, int out_size, void* d_ws, size_t ws_size,
                              hipStream_t stream) {
    const float* x_in = (const float*)d_in[0];
    const int*   mask = (const int*)d_in[1];
    const float* btab = (const float*)d_in[2];
    const float* ln_g = (const float*)d_in[3];
    const float* ln_b = (const float*)d_in[4];
    const float* wq = (const float*)d_in[5];
    const float* bq = (const float*)d_in[6];
    const float* wk = (const float*)d_in[7];
    const float* bk = (const float*)d_in[8];
    const float* wv = (const float*)d_in[9];
    const float* bv = (const float*)d_in[10];
    const float* wo = (const float*)d_in[11];
    const float* bo = (const float*)d_in[12];
    const float* cg = (const float*)d_in[13];
    const float* cb = (const float*)d_in[14];
    const float* w1 = (const float*)d_in[15];
    const float* b1 = (const float*)d_in[16];
    const float* w2 = (const float*)d_in[17];
    const float* b2 = (const float*)d_in[18];
    float* out = (float*)d_out;

    // Workspace layout (~137 MB), regions reused across stage lifetimes.
    char* p = (char*)d_ws;
    const size_t F32SZ  = (size_t)M_ROWS * D_HID * sizeof(float);   // 33.5 MB
    const size_t BF16SZ = (size_t)M_ROWS * D_HID * sizeof(bf16_t);  // 16.8 MB
    float*  H  = (float*)p;  p += F32SZ;
    float*  X  = (float*)p;  p += F32SZ;
    bf16_t* Hb = (bf16_t*)p; p += BF16SZ;   // later: AO
    bf16_t* Qb = (bf16_t*)p; p += BF16SZ;   // later: Cb
    bf16_t* Kb = (bf16_t*)p;                // T (f32) spans Kb+Vt; T1b reuses Kb
    float*  T  = (float*)Kb;
    bf16_t* T1b = Kb;
    p += BF16SZ;
    bf16_t* Vt = (bf16_t*)p; p += BF16SZ;   // transposed V [b][d][s]
    bf16_t* Wqkv = (bf16_t*)p; p += (size_t)N_L * 768 * 256 * sizeof(bf16_t);  // packed
    bf16_t* Wrest = (bf16_t*)p;             // Wo,W1,W2: 3 * L * 65536 bf16
    bf16_t* AO = Hb;
    bf16_t* Cb = Qb;

    const int WELEMS = N_L * D_HID * D_HID;   // 196608 per weight tensor
    transpose_w<<<dim3(WELEMS / 256), dim3(256), 0, stream>>>(wq, Wqkv + 0 * 65536, 3 * 65536);
    transpose_w<<<dim3(WELEMS / 256), dim3(256), 0, stream>>>(wk, Wqkv + 1 * 65536, 3 * 65536);
    transpose_w<<<dim3(WELEMS / 256), dim3(256), 0, stream>>>(wv, Wqkv + 2 * 65536, 3 * 65536);
    transpose_w<<<dim3(WELEMS / 256), dim3(256), 0, stream>>>(wo, Wrest + (size_t)0 * WELEMS, 65536);
    transpose_w<<<dim3(WELEMS / 256), dim3(256), 0, stream>>>(w1, Wrest + (size_t)1 * WELEMS, 65536);
    transpose_w<<<dim3(WELEMS / 256), dim3(256), 0, stream>>>(w2, Wrest + (size_t)2 * WELEMS, 65536);

    const dim3 gblk(256, 1, 1);
    const dim3 grid_qkv(M_ROWS / 128, 6, 1);
    const dim3 grid_one(M_ROWS / 128, 2, 1);

    for (int j = 0; j < N_L; ++j) {
        const bf16_t* WQKVj = Wqkv + (size_t)j * 3 * 65536;
        const bf16_t* WOt = Wrest + ((size_t)0 * N_L + j) * 65536;
        const bf16_t* W1t = Wrest + ((size_t)1 * N_L + j) * 65536;
        const bf16_t* W2t = Wrest + ((size_t)2 * N_L + j) * 65536;

        ln_fwd<<<dim3(M_ROWS / 4), gblk, 0, stream>>>(j == 0 ? x_in : X,
                                                      ln_g + j * D_HID, ln_b + j * D_HID, H, Hb);
        gemm_qkv<<<grid_qkv, gblk, 0, stream>>>(Hb, WQKVj, bq + j * D_HID, bk + j * D_HID,
                                                bv + j * D_HID, Qb, Kb, Vt);
        attn_fwd<<<dim3(N_B * 16, 1, 1), gblk, 0, stream>>>(Qb, Kb, Vt, btab, mask, AO);
        gemm_one<2><<<grid_one, gblk, 0, stream>>>(AO, WOt, bo + j * D_HID, T, nullptr);
        ln_res_ln<<<dim3(M_ROWS / 4), gblk, 0, stream>>>(T, H, ln_g + j * D_HID, ln_b + j * D_HID,
                                                         cg + j * D_HID, cb + j * D_HID, X, Cb);
        gemm_one<1><<<grid_one, gblk, 0, stream>>>(Cb, W1t, b1 + j * D_HID, T1b, nullptr);
        gemm_one<3><<<grid_one, gblk, 0, stream>>>(T1b, W2t, b2 + j * D_HID,
                                                   (j == N_L - 1) ? (void*)out : (void*)X, X);
    }
}

// Round 5
// 687.704 us; speedup vs baseline: 1.4837x; 1.0408x over previous
//
#include <hip/hip_runtime.h>
#include <hip/hip_bf16.h>
#include <math.h>

// Problem constants (B=64, S=512, D=256, L=3)
#define D_HID 256
#define N_B   64
#define S_LEN 512
#define N_L   3
#define M_ROWS (N_B * S_LEN)   // 32768 rows

typedef __bf16 bf16_t;
typedef __bf16 bf16x8 __attribute__((ext_vector_type(8)));
typedef __bf16 bf16x4 __attribute__((ext_vector_type(4)));
typedef float  f32x4  __attribute__((ext_vector_type(4)));
typedef unsigned int u32;

__device__ __forceinline__ f32x4 mfma16(bf16x8 a, bf16x8 b, f32x4 c) {
    return __builtin_amdgcn_mfma_f32_16x16x32_bf16(a, b, c, 0, 0, 0);
}

// async global->LDS, 16B per lane; LDS dest = wave-uniform base + lane*16
__device__ __forceinline__ void gld_lds16(const void* g, void* l) {
    __builtin_amdgcn_global_load_lds((const __attribute__((address_space(1))) u32*)g,
                                     (__attribute__((address_space(3))) u32*)l, 16, 0, 0);
}

__device__ __forceinline__ u32 pk_bf16(float a, float b) {
    return (u32)(__hip_bfloat16_raw(__hip_bfloat16(a)).x) |
           ((u32)(__hip_bfloat16_raw(__hip_bfloat16(b)).x) << 16);
}

// ---------------------------------------------------------------------------
// All-in-one weight transpose + bf16: 6 tensors, grid (768, 6).
// t in 0..2 -> Wqkv packed [l][t][n][k]; t in 3..5 -> Wrest [(t-3)][l][n][k].
// ---------------------------------------------------------------------------
__global__ __launch_bounds__(256) void transpose_all(const float* __restrict__ wq,
                                                     const float* __restrict__ wk,
                                                     const float* __restrict__ wv,
                                                     const float* __restrict__ wo,
                                                     const float* __restrict__ w1,
                                                     const float* __restrict__ w2,
                                                     bf16_t* __restrict__ Wqkv,
                                                     bf16_t* __restrict__ Wrest) {
    const int t = blockIdx.y;
    const float* src = t == 0 ? wq : t == 1 ? wk : t == 2 ? wv
                     : t == 3 ? wo : t == 4 ? w1 : w2;
    const int i = blockIdx.x * 256 + threadIdx.x;   // [0, 196608)
    const int k = i & 255;
    const int n = (i >> 8) & 255;
    const int l = i >> 16;
    const bf16_t v = (bf16_t)src[((size_t)l << 16) + ((size_t)k << 8) + n];
    if (t < 3) Wqkv[(size_t)l * 3 * 65536 + t * 65536 + n * 256 + k] = v;
    else       Wrest[(size_t)(t - 3) * 196608 + l * 65536 + n * 256 + k] = v;
}

// ---------------------------------------------------------------------------
// LayerNorm: H = LN(in)*g + b  (f32 out + bf16 copy). One wave per row.
// ---------------------------------------------------------------------------
__global__ __launch_bounds__(256) void ln_fwd(const float* __restrict__ in,
                                              const float* __restrict__ g,
                                              const float* __restrict__ b,
                                              float* __restrict__ H,
                                              bf16_t* __restrict__ Hb) {
    int row  = blockIdx.x * 4 + (threadIdx.x >> 6);
    int lane = threadIdx.x & 63;
    float4 x = ((const float4*)(in + (size_t)row * D_HID))[lane];
    float s  = x.x + x.y + x.z + x.w;
    float sq = x.x * x.x + x.y * x.y + x.z * x.z + x.w * x.w;
#pragma unroll
    for (int o = 1; o < 64; o <<= 1) { s += __shfl_xor(s, o); sq += __shfl_xor(sq, o); }
    float mean = s * (1.f / D_HID);
    float rstd = rsqrtf(sq * (1.f / D_HID) - mean * mean + 1e-5f);
    float4 gv = ((const float4*)g)[lane];
    float4 bv = ((const float4*)b)[lane];
    float4 h;
    h.x = (x.x - mean) * rstd * gv.x + bv.x;
    h.y = (x.y - mean) * rstd * gv.y + bv.y;
    h.z = (x.z - mean) * rstd * gv.z + bv.z;
    h.w = (x.w - mean) * rstd * gv.w + bv.w;
    ((float4*)(H + (size_t)row * D_HID))[lane] = h;
    bf16x4 hb = { (bf16_t)h.x, (bf16_t)h.y, (bf16_t)h.z, (bf16_t)h.w };
    *((bf16x4*)(Hb + (size_t)row * D_HID) + lane) = hb;
}

// ---------------------------------------------------------------------------
// Fused: X = H + LN(T)*g + b ; Cb = bf16( LN(X)*cg + cb ). One wave per row.
// ---------------------------------------------------------------------------
__global__ __launch_bounds__(256) void ln_res_ln(const float* __restrict__ T,
                                                 const float* __restrict__ H,
                                                 const float* __restrict__ g,
                                                 const float* __restrict__ b,
                                                 const float* __restrict__ cg,
                                                 const float* __restrict__ cb,
                                                 float* __restrict__ X,
                                                 bf16_t* __restrict__ Cb) {
    int row  = blockIdx.x * 4 + (threadIdx.x >> 6);
    int lane = threadIdx.x & 63;
    float4 t = ((const float4*)(T + (size_t)row * D_HID))[lane];
    float s  = t.x + t.y + t.z + t.w;
    float sq = t.x * t.x + t.y * t.y + t.z * t.z + t.w * t.w;
#pragma unroll
    for (int o = 1; o < 64; o <<= 1) { s += __shfl_xor(s, o); sq += __shfl_xor(sq, o); }
    float mean = s * (1.f / D_HID);
    float rstd = rsqrtf(sq * (1.f / D_HID) - mean * mean + 1e-5f);
    float4 gv = ((const float4*)g)[lane];
    float4 bv = ((const float4*)b)[lane];
    float4 hh = ((const float4*)(H + (size_t)row * D_HID))[lane];
    float4 x;
    x.x = hh.x + (t.x - mean) * rstd * gv.x + bv.x;
    x.y = hh.y + (t.y - mean) * rstd * gv.y + bv.y;
    x.z = hh.z + (t.z - mean) * rstd * gv.z + bv.z;
    x.w = hh.w + (t.w - mean) * rstd * gv.w + bv.w;
    ((float4*)(X + (size_t)row * D_HID))[lane] = x;
    // second LN
    float s2  = x.x + x.y + x.z + x.w;
    float sq2 = x.x * x.x + x.y * x.y + x.z * x.z + x.w * x.w;
#pragma unroll
    for (int o = 1; o < 64; o <<= 1) { s2 += __shfl_xor(s2, o); sq2 += __shfl_xor(sq2, o); }
    float mean2 = s2 * (1.f / D_HID);
    float rstd2 = rsqrtf(sq2 * (1.f / D_HID) - mean2 * mean2 + 1e-5f);
    float4 cgv = ((const float4*)cg)[lane];
    float4 cbv = ((const float4*)cb)[lane];
    bf16x4 c = { (bf16_t)((x.x - mean2) * rstd2 * cgv.x + cbv.x),
                 (bf16_t)((x.y - mean2) * rstd2 * cgv.y + cbv.y),
                 (bf16_t)((x.z - mean2) * rstd2 * cgv.z + cbv.z),
                 (bf16_t)((x.w - mean2) * rstd2 * cgv.w + cbv.w) };
    *((bf16x4*)(Cb + (size_t)row * D_HID) + lane) = c;
}

// ---------------------------------------------------------------------------
// GEMM core v2: 128x128 tile, BK=64, 2-phase double-buffered LDS pipeline.
// stage(t+1) issued first, compute(t), then vmcnt(0)+barrier — stage latency
// hides under compute (T3-minimum). XOR swizzle as before (src-permuted
// global + XOR on ds_read, linear LDS dest for global_load_lds).
// ---------------------------------------------------------------------------
__device__ __forceinline__ void stage_tile(const bf16_t* __restrict__ A,
                                           const bf16_t* __restrict__ W,
                                           int m0, int n0, int kt,
                                           bf16_t* As, bf16_t* Bs) {
    const int lane = threadIdx.x & 63;
    const int wid  = threadIdx.x >> 6;
#pragma unroll
    for (int i = 0; i < 4; ++i) {
        const int base8 = i * 256 + wid * 64;          // wave-uniform
        const int idx8  = base8 + lane;
        const int row   = idx8 >> 3;
        const int sc8   = (idx8 & 7) ^ (row & 7);      // inverse swizzle on SRC
        gld_lds16(A + (size_t)(m0 + row) * D_HID + kt * 64 + sc8 * 8, As + base8 * 8);
        gld_lds16(W + (size_t)(n0 + row) * D_HID + kt * 64 + sc8 * 8, Bs + base8 * 8);
    }
}

__device__ __forceinline__ void compute_tile(const bf16_t* As, const bf16_t* Bs,
                                             f32x4 (&acc)[4][4]) {
    const int lane = threadIdx.x & 63;
    const int wid  = threadIdx.x >> 6;
    const int wm = wid >> 1, wn = wid & 1;
    const int r = lane & 15, g = lane >> 4;
#pragma unroll
    for (int ks = 0; ks < 2; ++ks) {
        bf16x8 af[4], bfr[4];
#pragma unroll
        for (int mt = 0; mt < 4; ++mt) {
            const int row = wm * 64 + mt * 16 + r;
            const int c8  = (ks * 4 + g) ^ (row & 7);  // swizzle on READ
            af[mt] = *(const bf16x8*)(As + row * 64 + c8 * 8);
        }
#pragma unroll
        for (int nt = 0; nt < 4; ++nt) {
            const int row = wn * 64 + nt * 16 + r;
            const int c8  = (ks * 4 + g) ^ (row & 7);
            bfr[nt] = *(const bf16x8*)(Bs + row * 64 + c8 * 8);
        }
#pragma unroll
        for (int mt = 0; mt < 4; ++mt)
#pragma unroll
            for (int nt = 0; nt < 4; ++nt)
                acc[mt][nt] = mfma16(af[mt], bfr[nt], acc[mt][nt]);
    }
}

__device__ __forceinline__ void gemm_core(const bf16_t* __restrict__ A,
                                          const bf16_t* __restrict__ W,
                                          int m0, int n0,
                                          bf16_t (&As)[2][8192], bf16_t (&Bs)[2][8192],
                                          f32x4 (&acc)[4][4]) {
    stage_tile(A, W, m0, n0, 0, As[0], Bs[0]);
    asm volatile("s_waitcnt vmcnt(0)" ::: "memory");
    __builtin_amdgcn_s_barrier();
#pragma unroll
    for (int kt = 0; kt < 4; ++kt) {
        const int cur = kt & 1;
        if (kt < 3) stage_tile(A, W, m0, n0, kt + 1, As[cur ^ 1], Bs[cur ^ 1]);
        compute_tile(As[cur], Bs[cur], acc);
        if (kt < 3) {
            asm volatile("s_waitcnt vmcnt(0)" ::: "memory");
            __builtin_amdgcn_s_barrier();
        }
    }
}

// Fused QKV GEMM: Wp packed [768][256], cols 0-255->Qb, 256-511->Kb,
// 512-767 -> Vt (transposed [b][d][s]). Grid (M/128, 6).
__global__ __launch_bounds__(256) void gemm_qkv(const bf16_t* __restrict__ A,
                                                const bf16_t* __restrict__ Wp,
                                                const float* __restrict__ bq,
                                                const float* __restrict__ bk,
                                                const float* __restrict__ bv,
                                                bf16_t* __restrict__ Qb,
                                                bf16_t* __restrict__ Kb,
                                                bf16_t* __restrict__ Vt) {
    __shared__ bf16_t As[2][8192], Bs[2][8192];
    f32x4 acc[4][4] = {};
    const int m0 = blockIdx.x * 128, n0 = blockIdx.y * 128;
    gemm_core(A, Wp, m0, n0, As, Bs, acc);
    const int lane = threadIdx.x & 63, wid = threadIdx.x >> 6;
    const int wm = wid >> 1, wn = wid & 1, r = lane & 15, g = lane >> 4;
#pragma unroll
    for (int nt = 0; nt < 4; ++nt) {
        const int col = n0 + wn * 64 + nt * 16 + r;
        const int t = col >> 8, cc = col & 255;
        const float bias = (t == 0 ? bq : t == 1 ? bk : bv)[cc];
#pragma unroll
        for (int mt = 0; mt < 4; ++mt)
#pragma unroll
            for (int rr = 0; rr < 4; ++rr) {
                const int row = m0 + wm * 64 + mt * 16 + g * 4 + rr;
                const float v = acc[mt][nt][rr] + bias;
                if (t == 0)      Qb[(size_t)row * D_HID + cc] = (bf16_t)v;
                else if (t == 1) Kb[(size_t)row * D_HID + cc] = (bf16_t)v;
                else             Vt[((size_t)(row >> 9) * D_HID + cc) * S_LEN + (row & 511)] = (bf16_t)v;
            }
    }
}

// Generic GEMM, N=256. EPI 1: gelu->bf16  2: f32  3: addsrc+ -> f32
template <int EPI>
__global__ __launch_bounds__(256) void gemm_one(const bf16_t* __restrict__ A,
                                                const bf16_t* __restrict__ W,
                                                const float* __restrict__ bias,
                                                void* __restrict__ outp,
                                                const float* __restrict__ addsrc) {
    __shared__ bf16_t As[2][8192], Bs[2][8192];
    f32x4 acc[4][4] = {};
    const int m0 = blockIdx.x * 128, n0 = blockIdx.y * 128;
    gemm_core(A, W, m0, n0, As, Bs, acc);
    const int lane = threadIdx.x & 63, wid = threadIdx.x >> 6;
    const int wm = wid >> 1, wn = wid & 1, r = lane & 15, g = lane >> 4;
#pragma unroll
    for (int nt = 0; nt < 4; ++nt) {
        const int col = n0 + wn * 64 + nt * 16 + r;
        const float bv = bias[col];
#pragma unroll
        for (int mt = 0; mt < 4; ++mt)
#pragma unroll
            for (int rr = 0; rr < 4; ++rr) {
                const size_t idx = (size_t)(m0 + wm * 64 + mt * 16 + g * 4 + rr) * D_HID + col;
                float v = acc[mt][nt][rr] + bv;
                if constexpr (EPI == 1) {
                    v = 0.5f * v * (1.f + erff(v * 0.70710678118654752f));
                    ((bf16_t*)outp)[idx] = (bf16_t)v;
                } else if constexpr (EPI == 2) {
                    ((float*)outp)[idx] = v;
                } else {
                    ((float*)outp)[idx] = addsrc[idx] + v;
                }
            }
    }
}

// ---------------------------------------------------------------------------
// Flash attention v5. Grid 1024 (XCD-chunked), 4 waves, QBLK=32.
// v4 + Q-hoist (16 bf16x8 in regs, loaded once) + V-prefetch (8 bf16x8
// issued at tile top, consumed after B2 — latency hides under QK+softmax).
// ---------------------------------------------------------------------------
__global__ __launch_bounds__(256, 2) void attn_fwd(const bf16_t* __restrict__ Q,
                                                   const bf16_t* __restrict__ K,
                                                   const bf16_t* __restrict__ Vt,
                                                   const float* __restrict__ btab,
                                                   const int* __restrict__ mask,
                                                   bf16_t* __restrict__ AO) {
    __shared__ float  bias_lds[1024];
    __shared__ float  mask_add[512];
    __shared__ bf16_t P_lds[32 * 64];        // 4KB, row stride 128B, XOR-swizzled
    __shared__ float  m_part[4][32], l_part[4][32];
    __shared__ bf16_t o_lds[32][264];        // 16.5KB, row stride 528B

    const int tid = threadIdx.x, lane = tid & 63, w = tid >> 6;
    const int r = lane & 15, g = lane >> 4;

    // XCD-chunked mapping: 8 batches per XCD -> K/V L2-resident
    const int lid = blockIdx.x;
    const int xcd = lid & 7, slot = lid >> 3;
    const int b  = xcd * 8 + (slot >> 4);
    const int q0 = (slot & 15) * 32;

    for (int i = tid; i < 1024; i += 256) {
        const int rel = i - 512;
        const int bucket = (rel < 0) ? (511 - rel) : rel;
        bias_lds[i] = btab[bucket];
    }
    for (int i = tid; i < 512; i += 256)
        mask_add[i] = mask[b * S_LEN + i] ? 0.f : -3.0e38f;
    __syncthreads();

    const bf16_t* Qp = Q  + ((size_t)b * S_LEN + q0) * D_HID;
    const bf16_t* Kp = K  + (size_t)b * S_LEN * D_HID;
    const bf16_t* Vp = Vt + (size_t)b * D_HID * S_LEN;

    // ---- Q-hoist: per-lane Q fragments for both q-sub-blocks, all K-slices
    bf16x8 qf[2][8];
#pragma unroll
    for (int ks = 0; ks < 8; ++ks) {
        qf[0][ks] = *(const bf16x8*)(Qp + (size_t)r * D_HID + ks * 32 + g * 8);
        qf[1][ks] = *(const bf16x8*)(Qp + (size_t)(16 + r) * D_HID + ks * 32 + g * 8);
    }

    f32x4 oacc[4][2] = {};                   // [nt: d-16-blocks][qb]
    float m_run[2] = {-3.0e38f, -3.0e38f};
    float l_run[2] = {0.f, 0.f};

#pragma unroll 1
    for (int kt = 0; kt < 8; ++kt) {
        const int k0 = kt * 64;
        // ---- V-prefetch for this tile (consumed after B2)
        bf16x8 vpre[2][4];
#pragma unroll
        for (int ks = 0; ks < 2; ++ks)
#pragma unroll
            for (int nt = 0; nt < 4; ++nt)
                vpre[ks][nt] = *(const bf16x8*)(Vp + (size_t)(w * 64 + nt * 16 + r) * S_LEN
                                                     + k0 + ks * 32 + g * 8);
        // ---- QK^T swapped: lane holds S^T[k = k0+w*16+g*4+rr][q = q0+qb*16+r]
        f32x4 sacc[2] = {};
#pragma unroll
        for (int ks = 0; ks < 8; ++ks) {
            const int dk = ks * 32 + g * 8;
            bf16x8 kf = *(const bf16x8*)(Kp + (size_t)(k0 + w * 16 + r) * D_HID + dk);
            sacc[0] = mfma16(kf, qf[0][ks], sacc[0]);
            sacc[1] = mfma16(kf, qf[1][ks], sacc[1]);
        }
        // ---- bias + mask + per-wave max (in-lane + shfl over g)
        float mx[2] = {-3.0e38f, -3.0e38f};
#pragma unroll
        for (int qb = 0; qb < 2; ++qb) {
            const int qg = q0 + qb * 16 + r;
#pragma unroll
            for (int rr = 0; rr < 4; ++rr) {
                const int kg = k0 + w * 16 + g * 4 + rr;
                float ev = sacc[qb][rr] * 0.0625f + bias_lds[kg - qg + 512] + mask_add[kg];
                sacc[qb][rr] = ev;
                mx[qb] = fmaxf(mx[qb], ev);
            }
            mx[qb] = fmaxf(mx[qb], __shfl_xor(mx[qb], 16));
            mx[qb] = fmaxf(mx[qb], __shfl_xor(mx[qb], 32));
        }
        if (g == 0) { m_part[w][r] = mx[0]; m_part[w][16 + r] = mx[1]; }
        __syncthreads();                                   // B1
        float mnew[2], fac[2];
#pragma unroll
        for (int qb = 0; qb < 2; ++qb) {
            const int q = qb * 16 + r;
            const float tm = fmaxf(fmaxf(m_part[0][q], m_part[1][q]),
                                   fmaxf(m_part[2][q], m_part[3][q]));
            mnew[qb] = fmaxf(m_run[qb], tm);
            fac[qb]  = __expf(m_run[qb] - mnew[qb]);
            m_run[qb] = mnew[qb];
        }
        // ---- P = exp(ev - m), l-partials, pack bf16 -> swizzled LDS
#pragma unroll
        for (int qb = 0; qb < 2; ++qb) {
            const float p0 = __expf(sacc[qb][0] - mnew[qb]);
            const float p1 = __expf(sacc[qb][1] - mnew[qb]);
            const float p2 = __expf(sacc[qb][2] - mnew[qb]);
            const float p3 = __expf(sacc[qb][3] - mnew[qb]);
            float ls = p0 + p1 + p2 + p3;
            ls += __shfl_xor(ls, 16);
            ls += __shfl_xor(ls, 32);
            if (g == 0) l_part[w][qb * 16 + r] = ls;
            const int q = qb * 16 + r;
            const int u = (2 * w + (g >> 1)) ^ (q & 7);    // 16B-unit XOR swizzle
            uint2 pv; pv.x = pk_bf16(p0, p1); pv.y = pk_bf16(p2, p3);
            *(uint2*)((char*)P_lds + q * 128 + u * 16 + (g & 1) * 8) = pv;
        }
        __syncthreads();                                   // B2
        // ---- l update + O rescale
#pragma unroll
        for (int qb = 0; qb < 2; ++qb) {
            const int q = qb * 16 + r;
            const float lt = l_part[0][q] + l_part[1][q] + l_part[2][q] + l_part[3][q];
            l_run[qb] = l_run[qb] * fac[qb] + lt;
        }
#pragma unroll
        for (int nt = 0; nt < 4; ++nt)
#pragma unroll
            for (int qb = 0; qb < 2; ++qb)
#pragma unroll
                for (int rr = 0; rr < 4; ++rr)
                    oacc[nt][qb][rr] *= fac[qb];
        // ---- PV (O^T): A = prefetched V regs, B = P rows (swizzled LDS)
#pragma unroll
        for (int ks = 0; ks < 2; ++ks) {
            bf16x8 pf[2];
#pragma unroll
            for (int qb = 0; qb < 2; ++qb) {
                const int q = qb * 16 + r;
                const int u = (ks * 4 + g) ^ (q & 7);
                pf[qb] = *(const bf16x8*)((const char*)P_lds + q * 128 + u * 16);
            }
            __builtin_amdgcn_s_setprio(1);
#pragma unroll
            for (int nt = 0; nt < 4; ++nt) {
                oacc[nt][0] = mfma16(vpre[ks][nt], pf[0], oacc[nt][0]);
                oacc[nt][1] = mfma16(vpre[ks][nt], pf[1], oacc[nt][1]);
            }
            __builtin_amdgcn_s_setprio(0);
        }
    }
    // ---- epilogue: scale 1/l (same across waves), transpose via LDS, store
    const float inv_l[2] = { 1.f / fmaxf(l_run[0], 1e-30f),
                             1.f / fmaxf(l_run[1], 1e-30f) };
#pragma unroll
    for (int nt = 0; nt < 4; ++nt)
#pragma unroll
        for (int qb = 0; qb < 2; ++qb) {
            const int q = qb * 16 + r;
            const int d = w * 64 + nt * 16 + g * 4;
            bf16x4 ob = { (bf16_t)(oacc[nt][qb][0] * inv_l[qb]),
                          (bf16_t)(oacc[nt][qb][1] * inv_l[qb]),
                          (bf16_t)(oacc[nt][qb][2] * inv_l[qb]),
                          (bf16_t)(oacc[nt][qb][3] * inv_l[qb]) };
            *(bf16x4*)&o_lds[q][d] = ob;
        }
    __syncthreads();
    bf16_t* Op = AO + ((size_t)b * S_LEN + q0) * D_HID;
#pragma unroll
    for (int it = 0; it < 4; ++it) {
        const int idx = it * 256 + tid;      // 1024 units = 32 rows x 32 x 16B
        const int row = idx >> 5, u = idx & 31;
        bf16x8 vv = *(const bf16x8*)&o_lds[row][u * 8];
        *(bf16x8*)(Op + (size_t)row * D_HID + u * 8) = vv;
    }
}

// ---------------------------------------------------------------------------
extern "C" void kernel_launch(void* const* d_in, const int* in_sizes, int n_in,
                              void* d_out, int out_size, void* d_ws, size_t ws_size,
                              hipStream_t stream) {
    const float* x_in = (const float*)d_in[0];
    const int*   mask = (const int*)d_in[1];
    const float* btab = (const float*)d_in[2];
    const float* ln_g = (const float*)d_in[3];
    const float* ln_b = (const float*)d_in[4];
    const float* wq = (const float*)d_in[5];
    const float* bq = (const float*)d_in[6];
    const float* wk = (const float*)d_in[7];
    const float* bk = (const float*)d_in[8];
    const float* wv = (const float*)d_in[9];
    const float* bv = (const float*)d_in[10];
    const float* wo = (const float*)d_in[11];
    const float* bo = (const float*)d_in[12];
    const float* cg = (const float*)d_in[13];
    const float* cb = (const float*)d_in[14];
    const float* w1 = (const float*)d_in[15];
    const float* b1 = (const float*)d_in[16];
    const float* w2 = (const float*)d_in[17];
    const float* b2 = (const float*)d_in[18];
    float* out = (float*)d_out;

    // Workspace layout (~137 MB), regions reused across stage lifetimes.
    char* p = (char*)d_ws;
    const size_t F32SZ  = (size_t)M_ROWS * D_HID * sizeof(float);   // 33.5 MB
    const size_t BF16SZ = (size_t)M_ROWS * D_HID * sizeof(bf16_t);  // 16.8 MB
    float*  H  = (float*)p;  p += F32SZ;
    float*  X  = (float*)p;  p += F32SZ;
    bf16_t* Hb = (bf16_t*)p; p += BF16SZ;   // later: AO
    bf16_t* Qb = (bf16_t*)p; p += BF16SZ;   // later: Cb
    bf16_t* Kb = (bf16_t*)p;                // T (f32) spans Kb+Vt; T1b reuses Kb
    float*  T  = (float*)Kb;
    bf16_t* T1b = Kb;
    p += BF16SZ;
    bf16_t* Vt = (bf16_t*)p; p += BF16SZ;   // transposed V [b][d][s]
    bf16_t* Wqkv = (bf16_t*)p; p += (size_t)N_L * 768 * 256 * sizeof(bf16_t);  // packed
    bf16_t* Wrest = (bf16_t*)p;             // Wo,W1,W2: 3 * L * 65536 bf16
    bf16_t* AO = Hb;
    bf16_t* Cb = Qb;

    transpose_all<<<dim3(768, 6), dim3(256), 0, stream>>>(wq, wk, wv, wo, w1, w2, Wqkv, Wrest);

    const dim3 gblk(256, 1, 1);
    const dim3 grid_qkv(M_ROWS / 128, 6, 1);
    const dim3 grid_one(M_ROWS / 128, 2, 1);

    for (int j = 0; j < N_L; ++j) {
        const bf16_t* WQKVj = Wqkv + (size_t)j * 3 * 65536;
        const bf16_t* WOt = Wrest + ((size_t)0 * N_L + j) * 65536;
        const bf16_t* W1t = Wrest + ((size_t)1 * N_L + j) * 65536;
        const bf16_t* W2t = Wrest + ((size_t)2 * N_L + j) * 65536;

        ln_fwd<<<dim3(M_ROWS / 4), gblk, 0, stream>>>(j == 0 ? x_in : X,
                                                      ln_g + j * D_HID, ln_b + j * D_HID, H, Hb);
        gemm_qkv<<<grid_qkv, gblk, 0, stream>>>(Hb, WQKVj, bq + j * D_HID, bk + j * D_HID,
                                                bv + j * D_HID, Qb, Kb, Vt);
        attn_fwd<<<dim3(N_B * 16, 1, 1), gblk, 0, stream>>>(Qb, Kb, Vt, btab, mask, AO);
        gemm_one<2><<<grid_one, gblk, 0, stream>>>(AO, WOt, bo + j * D_HID, T, nullptr);
        ln_res_ln<<<dim3(M_ROWS / 4), gblk, 0, stream>>>(T, H, ln_g + j * D_HID, ln_b + j * D_HID,
                                                         cg + j * D_HID, cb + j * D_HID, X, Cb);
        gemm_one<1><<<grid_one, gblk, 0, stream>>>(Cb, W1t, b1 + j * D_HID, T1b, nullptr);
        gemm_one<3><<<grid_one, gblk, 0, stream>>>(T1b, W2t, b2 + j * D_HID,
                                                   (j == N_L - 1) ? (void*)out : (void*)X, X);
    }
}